// Round 25
// baseline (37.183 us; speedup 1.0000x reference)
//
#include <hip/hip_runtime.h>

// Problem constants: B=8, N=2048, M=2048, D=128
#define B_DIM 8
#define N_DIM 2048
#define M_DIM 2048
#define D_DIM 128
#define NT_TILES 8          // tiles of 64 cols per block

typedef __bf16 bf16_t;
typedef bf16_t bf16x8 __attribute__((ext_vector_type(8)));
typedef float f32x4 __attribute__((ext_vector_type(4)));
typedef float f32x16 __attribute__((ext_vector_type(16)));

// lgkm-only barrier: never drains vmcnt -> global stores / prefetch loads
// stay in flight across tile boundaries.
__device__ __forceinline__ void lgkm_barrier() {
    asm volatile("s_waitcnt lgkmcnt(0)" ::: "memory");
    __builtin_amdgcn_s_barrier();
}

// ---------------------------------------------------------------------------
// Champion body (32x32x16 MFMA, full-line NONTEMPORAL stores, fused staging,
// XCD-batch swizzle, lgkm-only barriers, prefetch-before-stores) at
// 16 WAVES/CU:
//
// Wave-scaling law (R16/R19, VGPR-clean points): achieved write BW scales
// with resident waves/CU: 4w ~1.5, 8w ~3.5-4, 12w ~4.7 TB/s (R19, 33.2us).
// This round: A panel shrunk to 64 rows (16KB) => LDS = 16A + 16B + norms
// ~= 33KB => 4 blocks/CU = 16 waves. Per-wave state shrunk to fit the
// 128-VGPR natural cap for 4 waves/SIMD: each wave owns 32x32
// (af[8]=32 + acc=16 + prefetch=32 + misc ~= 105 VGPR). NO min-waves
// launch bound (the (256,3)/(512,4) remat sabotage, thrice confirmed).
// Cost under test: barrier-pairs per output byte double vs champion.
// ---------------------------------------------------------------------------
__global__ __launch_bounds__(256) void fused_dist_kernel(
    const float* __restrict__ L, const float* __restrict__ R,
    float* __restrict__ out)
{
    __shared__ bf16x8 Als[1024];   // 16 KB: A panel (64 rows), 4 groups
    __shared__ bf16x8 Bls[1024];   // 16 KB: B tile (64 rows), 4 groups
    __shared__ float nAs[64];
    __shared__ float nBs[64];

    // ---- XCD-locality decode: one batch per XCD (blockIdx round-robins XCDs)
    const int w   = blockIdx.x;    // [0, 1024)
    const int bz  = w & 7;         // XCD id == batch (1024 % 8 == 0)
    const int i   = w >> 3;        // [0, 128) within XCD
    const int bxg = i & 3;         // col-group: NT_TILES tiles of 64 cols
    const int by  = i >> 2;        // [0, 32) row-blocks of 64

    const int tid  = threadIdx.x;
    const int wid  = tid >> 6;         // 0..3
    const int lane = tid & 63;
    const int rA   = lane & 15;        // row within 16-row LDS group
    const int g2   = (lane >> 4) & 1;  // which 16-row group within 32
    const int hi   = lane >> 5;        // 0..1 (K-half / row-offset select)
    const int c32  = lane & 31;        // fragment row/col within 32
    const int r    = tid >> 4;         // staging: row within 16-row group
    const int gran = tid & 15;         // staging: 8-elem chunk

    const float* Asrc = L + ((size_t)bz * N_DIM + (size_t)by * 64) * D_DIM;
    const float* Rbat = R + (size_t)bz * M_DIM * D_DIM;

    // ---- initial stage: A panel, 64 rows (bf16 RNE + norms from SAME values)
    #pragma unroll
    for (int i2 = 0; i2 < 4; ++i2) {
        int row = i2 * 16 + r;
        float4 v0 = ((const float4*)Asrc)[(size_t)row * 32 + gran * 2];
        float4 v1 = ((const float4*)Asrc)[(size_t)row * 32 + gran * 2 + 1];
        bf16x8 p = { (bf16_t)v0.x, (bf16_t)v0.y, (bf16_t)v0.z, (bf16_t)v0.w,
                     (bf16_t)v1.x, (bf16_t)v1.y, (bf16_t)v1.z, (bf16_t)v1.w };
        Als[i2 * 256 + gran * 16 + (r ^ gran)] = p;
        float s = 0.0f;
        #pragma unroll
        for (int j = 0; j < 8; ++j) { float x = (float)p[j]; s = fmaf(x, x, s); }
        s += __shfl_xor(s, 1); s += __shfl_xor(s, 2);
        s += __shfl_xor(s, 4); s += __shfl_xor(s, 8);
        if (gran == 0) nAs[i2 * 16 + r] = s;
    }
    // ---- initial stage: B tile 0, 64 rows
    {
        const float* Bsrc = Rbat + (size_t)(bxg * NT_TILES) * 64 * D_DIM;
        #pragma unroll
        for (int i2 = 0; i2 < 4; ++i2) {
            int row = i2 * 16 + r;
            float4 v0 = ((const float4*)Bsrc)[(size_t)row * 32 + gran * 2];
            float4 v1 = ((const float4*)Bsrc)[(size_t)row * 32 + gran * 2 + 1];
            bf16x8 p = { (bf16_t)v0.x, (bf16_t)v0.y, (bf16_t)v0.z, (bf16_t)v0.w,
                         (bf16_t)v1.x, (bf16_t)v1.y, (bf16_t)v1.z, (bf16_t)v1.w };
            Bls[i2 * 256 + gran * 16 + (r ^ gran)] = p;
            float s = 0.0f;
            #pragma unroll
            for (int j = 0; j < 8; ++j) { float x = (float)p[j]; s = fmaf(x, x, s); }
            s += __shfl_xor(s, 1); s += __shfl_xor(s, 2);
            s += __shfl_xor(s, 4); s += __shfl_xor(s, 8);
            if (gran == 0) nBs[i2 * 16 + r] = s;
        }
    }
    lgkm_barrier();

    // ---- wave tile bases: 4 waves in 2x2; wave owns 32 rows x 32 cols
    const int wr = wid >> 1;           // 0..1 (row half)
    const int wc = wid & 1;            // 0..1 (col half)
    const int wM = wr * 32;
    const int wN = wc * 32;

    // ---- A fragments into registers (Als dead afterwards): af[s]
    bf16x8 af[8];
    #pragma unroll
    for (int s = 0; s < 8; ++s) {
        const int gr = s * 2 + hi;           // 16B k-granule
        const int grp = wr * 2 + g2;
        af[s] = Als[grp * 256 + gr * 16 + (rA ^ gr)];
    }

    // ---- tile loop (8 tiles of 64 cols)
    for (int t = 0; t < NT_TILES; ++t) {
        const int bx = bxg * NT_TILES + t;

        // 1. MFMA on current B tile (8 K-steps of 16, single acc chain)
        f32x16 acc = {};
        #pragma unroll
        for (int s = 0; s < 8; ++s) {
            const int gr = s * 2 + hi;
            const bf16x8 bfr = Bls[(wc * 2 + g2) * 256 + gr * 16 + (rA ^ gr)];
            acc = __builtin_amdgcn_mfma_f32_32x32x16_bf16(af[s], bfr, acc, 0, 0, 0);
        }

        // 2. prefetch next B tile (f32) into regs BEFORE any stores issue
        //    (vmcnt retires in-order: restage's wait stays counted, stores
        //     never force-drained)
        float4 pf0[4], pf1[4];
        if (t + 1 < NT_TILES) {
            const float* Bsrc = Rbat + (size_t)(bx + 1) * 64 * D_DIM;
            #pragma unroll
            for (int i2 = 0; i2 < 4; ++i2) {
                int row = i2 * 16 + r;
                pf0[i2] = ((const float4*)Bsrc)[(size_t)row * 32 + gran * 2];
                pf1[i2] = ((const float4*)Bsrc)[(size_t)row * 32 + gran * 2 + 1];
            }
        }

        // 3. epilogue + full-line NONTEMPORAL stores
        //    out-row = wM + g*8 + hi*4 + e,  out-col = bx*64 + wN + c32
        const size_t outBase =
            ((size_t)bz * N_DIM + (size_t)by * 64) * M_DIM + (size_t)bx * 64;
        const int col_l = wN + c32;
        const float r2 = nBs[col_l];
        float* ocol = out + outBase + col_l;
        #pragma unroll
        for (int g = 0; g < 4; ++g) {
            const int rowb = wM + g * 8 + hi * 4;
            const f32x4 l2q = *(const f32x4*)&nAs[rowb];
            #pragma unroll
            for (int e = 0; e < 4; ++e) {
                float d2 = fmaf(-2.0f, acc[g * 4 + e], l2q[e] + r2);
                d2 = fmaxf(d2, 0.0f);
                float sq = __builtin_amdgcn_sqrtf(d2);
                float o = __builtin_amdgcn_rcpf(1.0f + sq);
                __builtin_nontemporal_store(
                    o, ocol + (size_t)(rowb + e) * M_DIM);
            }
        }

        // 4. restage next B tile from prefetched regs (lgkm-only barriers)
        if (t + 1 < NT_TILES) {
            lgkm_barrier();                    // all waves done reading Bls/nBs
            #pragma unroll
            for (int i2 = 0; i2 < 4; ++i2) {
                bf16x8 p = { (bf16_t)pf0[i2].x, (bf16_t)pf0[i2].y,
                             (bf16_t)pf0[i2].z, (bf16_t)pf0[i2].w,
                             (bf16_t)pf1[i2].x, (bf16_t)pf1[i2].y,
                             (bf16_t)pf1[i2].z, (bf16_t)pf1[i2].w };
                Bls[i2 * 256 + gran * 16 + (r ^ gran)] = p;
                float s = 0.0f;
                #pragma unroll
                for (int j = 0; j < 8; ++j) { float x = (float)p[j]; s = fmaf(x, x, s); }
                s += __shfl_xor(s, 1); s += __shfl_xor(s, 2);
                s += __shfl_xor(s, 4); s += __shfl_xor(s, 8);
                if (gran == 0) nBs[i2 * 16 + r] = s;
            }
            lgkm_barrier();                    // staging visible
        }
    }
}

extern "C" void kernel_launch(void* const* d_in, const int* in_sizes, int n_in,
                              void* d_out, int out_size, void* d_ws, size_t ws_size,
                              hipStream_t stream) {
    const float* L = (const float*)d_in[0];
    const float* R = (const float*)d_in[1];
    float* out = (float*)d_out;

    // 1D grid: w&7 selects XCD (round-robin) == batch; 128 blocks per XCD.
    // 1024 blocks = exactly 4 blocks/CU (one generation, 16 waves/CU).
    dim3 grid(1024, 1, 1);
    dim3 block(256);
    fused_dist_kernel<<<grid, block, 0, stream>>>(L, R, out);
}

// Round 26
// 35.642 us; speedup vs baseline: 1.0432x; 1.0432x over previous
//
#include <hip/hip_runtime.h>

// Problem constants: B=8, N=2048, M=2048, D=128
#define B_DIM 8
#define N_DIM 2048
#define M_DIM 2048
#define D_DIM 128
#define NT_TILES 4          // tiles of 64 cols per block

typedef __bf16 bf16_t;
typedef bf16_t bf16x8 __attribute__((ext_vector_type(8)));
typedef float f32x4 __attribute__((ext_vector_type(4)));
typedef float f32x16 __attribute__((ext_vector_type(16)));

// lgkm-only barrier: never drains vmcnt -> global stores / prefetch loads
// stay in flight across tile boundaries.
__device__ __forceinline__ void lgkm_barrier() {
    asm volatile("s_waitcnt lgkmcnt(0)" ::: "memory");
    __builtin_amdgcn_s_barrier();
}

// ---------------------------------------------------------------------------
// R19 champion body (32x32x16 MFMA, 64-col B tiles, full-line NONTEMPORAL
// stores, fused staging, XCD-batch swizzle, lgkm-only barriers,
// prefetch-before-stores, NO min-waves bound) at GRID 1024 for a clean
// 3-blocks/CU test:
//
// R19 analysis: its -15% (39.1 -> 33.2) came from FINER TILE GRANULARITY
// (16KB restage quantum, shorter store bursts), not wave count -- grid 512
// was still 2 blocks/CU. R17's 12-wave attempt was invalidated by
// launch_bounds-induced 84-VGPR remat. This round: same per-tile structure,
// but each block covers 128x256 (NT_TILES=4) and grid = 1024: at 49KB LDS,
// 3 blocks/CU are resident (768 at once, 256 stagger in as blocks retire).
// Barrier-pairs per byte improves slightly (3/128KB vs 7/256KB). VGPR stays
// natural (~150, within 512-VGPR-pool / 3 waves per SIMD).
// ---------------------------------------------------------------------------
__global__ __launch_bounds__(256) void fused_dist_kernel(
    const float* __restrict__ L, const float* __restrict__ R,
    float* __restrict__ out)
{
    __shared__ bf16x8 Als[2048];   // 32 KB: A panel (128 rows), 8 groups
    __shared__ bf16x8 Bls[1024];   // 16 KB: B tile (64 rows), 4 groups
    __shared__ float nAs[128];
    __shared__ float nBs[64];

    // ---- XCD-locality decode: one batch per XCD (blockIdx round-robins XCDs)
    const int w   = blockIdx.x;    // [0, 1024)
    const int bz  = w & 7;         // XCD id == batch (1024 % 8 == 0)
    const int i   = w >> 3;        // [0, 128) within XCD
    const int bxg = i & 7;         // col-group: NT_TILES tiles of 64 cols
    const int by  = i >> 3;        // [0, 16) row-panels of 128

    const int tid  = threadIdx.x;
    const int wid  = tid >> 6;         // 0..3
    const int lane = tid & 63;
    const int rA   = lane & 15;        // row within 16-row LDS group
    const int g2   = (lane >> 4) & 1;  // which 16-row group within 32
    const int hi   = lane >> 5;        // 0..1 (K-half / row-offset select)
    const int c32  = lane & 31;        // fragment row/col within 32
    const int r    = tid >> 4;         // staging: row within 16-row group
    const int gran = tid & 15;         // staging: 8-elem chunk

    const float* Asrc = L + ((size_t)bz * N_DIM + (size_t)by * 128) * D_DIM;
    const float* Rbat = R + (size_t)bz * M_DIM * D_DIM;

    // ---- initial stage: A panel (bf16 RNE + norms from SAME rounded values)
    #pragma unroll
    for (int i2 = 0; i2 < 8; ++i2) {
        int row = i2 * 16 + r;
        float4 v0 = ((const float4*)Asrc)[(size_t)row * 32 + gran * 2];
        float4 v1 = ((const float4*)Asrc)[(size_t)row * 32 + gran * 2 + 1];
        bf16x8 p = { (bf16_t)v0.x, (bf16_t)v0.y, (bf16_t)v0.z, (bf16_t)v0.w,
                     (bf16_t)v1.x, (bf16_t)v1.y, (bf16_t)v1.z, (bf16_t)v1.w };
        Als[i2 * 256 + gran * 16 + (r ^ gran)] = p;
        float s = 0.0f;
        #pragma unroll
        for (int j = 0; j < 8; ++j) { float x = (float)p[j]; s = fmaf(x, x, s); }
        s += __shfl_xor(s, 1); s += __shfl_xor(s, 2);
        s += __shfl_xor(s, 4); s += __shfl_xor(s, 8);
        if (gran == 0) nAs[i2 * 16 + r] = s;
    }
    // ---- initial stage: B tile 0 (64 rows)
    {
        const float* Bsrc = Rbat + (size_t)(bxg * NT_TILES) * 64 * D_DIM;
        #pragma unroll
        for (int i2 = 0; i2 < 4; ++i2) {
            int row = i2 * 16 + r;
            float4 v0 = ((const float4*)Bsrc)[(size_t)row * 32 + gran * 2];
            float4 v1 = ((const float4*)Bsrc)[(size_t)row * 32 + gran * 2 + 1];
            bf16x8 p = { (bf16_t)v0.x, (bf16_t)v0.y, (bf16_t)v0.z, (bf16_t)v0.w,
                         (bf16_t)v1.x, (bf16_t)v1.y, (bf16_t)v1.z, (bf16_t)v1.w };
            Bls[i2 * 256 + gran * 16 + (r ^ gran)] = p;
            float s = 0.0f;
            #pragma unroll
            for (int j = 0; j < 8; ++j) { float x = (float)p[j]; s = fmaf(x, x, s); }
            s += __shfl_xor(s, 1); s += __shfl_xor(s, 2);
            s += __shfl_xor(s, 4); s += __shfl_xor(s, 8);
            if (gran == 0) nBs[i2 * 16 + r] = s;
        }
    }
    lgkm_barrier();

    // ---- wave tile bases: 4 waves in 2x2; wave owns 64 rows x 32 cols
    const int wr = wid >> 1;           // 0..1 (row half)
    const int wc = wid & 1;            // 0..1 (col half)
    const int wM = wr * 64;
    const int wN = wc * 32;

    // ---- A fragments into registers (Als dead afterwards): af[tm][s]
    bf16x8 af[2][8];
    #pragma unroll
    for (int s = 0; s < 8; ++s) {
        const int gr = s * 2 + hi;           // 16B k-granule
        #pragma unroll
        for (int tm = 0; tm < 2; ++tm) {
            const int grp = wr * 4 + tm * 2 + g2;
            af[tm][s] = Als[grp * 256 + gr * 16 + (rA ^ gr)];
        }
    }

    // ---- tile loop (4 tiles of 64 cols)
    for (int t = 0; t < NT_TILES; ++t) {
        const int bx = bxg * NT_TILES + t;

        // 1. MFMA on current B tile (8 K-steps of 16, 2 indep chains)
        f32x16 acc[2] = {};
        #pragma unroll
        for (int s = 0; s < 8; ++s) {
            const int gr = s * 2 + hi;
            const bf16x8 bfr = Bls[(wc * 2 + g2) * 256 + gr * 16 + (rA ^ gr)];
            acc[0] = __builtin_amdgcn_mfma_f32_32x32x16_bf16(
                af[0][s], bfr, acc[0], 0, 0, 0);
            acc[1] = __builtin_amdgcn_mfma_f32_32x32x16_bf16(
                af[1][s], bfr, acc[1], 0, 0, 0);
        }

        // 2. prefetch next B tile (f32) into regs BEFORE any stores issue
        //    (vmcnt retires in-order: restage's wait stays counted, stores
        //     never force-drained)
        float4 pf0[4], pf1[4];
        if (t + 1 < NT_TILES) {
            const float* Bsrc = Rbat + (size_t)(bx + 1) * 64 * D_DIM;
            #pragma unroll
            for (int i2 = 0; i2 < 4; ++i2) {
                int row = i2 * 16 + r;
                pf0[i2] = ((const float4*)Bsrc)[(size_t)row * 32 + gran * 2];
                pf1[i2] = ((const float4*)Bsrc)[(size_t)row * 32 + gran * 2 + 1];
            }
        }

        // 3. epilogue + full-line NONTEMPORAL stores
        //    out-row = wM + tm*32 + g*8 + hi*4 + e,  out-col = bx*64 + wN + c32
        const size_t outBase =
            ((size_t)bz * N_DIM + (size_t)by * 128) * M_DIM + (size_t)bx * 64;
        const int col_l = wN + c32;
        const float r2 = nBs[col_l];
        float* ocol = out + outBase + col_l;
        #pragma unroll
        for (int tm = 0; tm < 2; ++tm) {
            #pragma unroll
            for (int g = 0; g < 4; ++g) {
                const int rowb = wM + tm * 32 + g * 8 + hi * 4;
                const f32x4 l2q = *(const f32x4*)&nAs[rowb];
                #pragma unroll
                for (int e = 0; e < 4; ++e) {
                    float d2 = fmaf(-2.0f, acc[tm][g * 4 + e], l2q[e] + r2);
                    d2 = fmaxf(d2, 0.0f);
                    float sq = __builtin_amdgcn_sqrtf(d2);
                    float o = __builtin_amdgcn_rcpf(1.0f + sq);
                    __builtin_nontemporal_store(
                        o, ocol + (size_t)(rowb + e) * M_DIM);
                }
            }
        }

        // 4. restage next B tile from prefetched regs (lgkm-only barriers)
        if (t + 1 < NT_TILES) {
            lgkm_barrier();                    // all waves done reading Bls/nBs
            #pragma unroll
            for (int i2 = 0; i2 < 4; ++i2) {
                bf16x8 p = { (bf16_t)pf0[i2].x, (bf16_t)pf0[i2].y,
                             (bf16_t)pf0[i2].z, (bf16_t)pf0[i2].w,
                             (bf16_t)pf1[i2].x, (bf16_t)pf1[i2].y,
                             (bf16_t)pf1[i2].z, (bf16_t)pf1[i2].w };
                Bls[i2 * 256 + gran * 16 + (r ^ gran)] = p;
                float s = 0.0f;
                #pragma unroll
                for (int j = 0; j < 8; ++j) { float x = (float)p[j]; s = fmaf(x, x, s); }
                s += __shfl_xor(s, 1); s += __shfl_xor(s, 2);
                s += __shfl_xor(s, 4); s += __shfl_xor(s, 8);
                if (gran == 0) nBs[i2 * 16 + r] = s;
            }
            lgkm_barrier();                    // staging visible
        }
    }
}

extern "C" void kernel_launch(void* const* d_in, const int* in_sizes, int n_in,
                              void* d_out, int out_size, void* d_ws, size_t ws_size,
                              hipStream_t stream) {
    const float* L = (const float*)d_in[0];
    const float* R = (const float*)d_in[1];
    float* out = (float*)d_out;

    // 1D grid: w&7 selects XCD (round-robin) == batch; 128 blocks per XCD.
    // 1024 blocks @ 49KB LDS => 3 resident/CU (768 at once) + stagger churn.
    dim3 grid(1024, 1, 1);
    dim3 block(256);
    fused_dist_kernel<<<grid, block, 0, stream>>>(L, R, out);
}